// Round 13
// baseline (1145.150 us; speedup 1.0000x reference)
//
#include <hip/hip_runtime.h>
#include <hip/hip_bf16.h>

#define N_NODES 50000
#define N_EDGES 800000
#define DIM 128
#define NTILES (N_EDGES / 64)   // 12500 exactly
#define CHUNK_B 49              // 49 x 1024 = 50176 >= 50000 nodes
#define NODE_B 782              // ceil(50000/64)
#define OUTZ_B 512
#define SCAT_B 2048             // 8 sets x 256 blocks; set = bid&7 -> XCD heuristic

typedef __bf16 bf16x8 __attribute__((ext_vector_type(8)));
typedef float f32x4 __attribute__((ext_vector_type(4)));
typedef unsigned int u32x4 __attribute__((ext_vector_type(4)));

__device__ __forceinline__ unsigned short f2bf(float f) {
    unsigned u = __float_as_uint(f);
    u += 0x7fffu + ((u >> 16) & 1u);          // round-to-nearest-even
    return (unsigned short)(u >> 16);
}
__device__ __forceinline__ float bf2f(unsigned short s) {
    return __uint_as_float(((unsigned)s) << 16);
}
// hw-packed f32x2 -> bf16x2 (v_cvt_pk_bf16_f32 on gfx950), lo in low 16 bits
__device__ __forceinline__ unsigned pack_bf2(float lo, float hi) {
    __hip_bfloat162 h = __float22bfloat162_rn(make_float2(lo, hi));
    unsigned u;
    __builtin_memcpy(&u, &h, 4);
    return u;
}
__device__ __forceinline__ unsigned short f2bf_hw(float f) {
    __hip_bfloat16 h = __float2bfloat16(f);
    unsigned short s;
    __builtin_memcpy(&s, &h, 2);
    return s;
}

// ---- K1: block 0 = weight combine; blocks 1..512 = zero out.
// lin1 is LINEAR (no relu): gA = x@(W1@Wa) + (b1@Wa + b2), gB = x@(W1@Wb) + b1@Wb
// where Wa = W2a - W2b, Wb = W2b. Precompute WA'=W1@Wa, WB'=W1@Wb (bf16 MFMA).
__global__ __launch_bounds__(256, 1) void prep_kernel(
        const float* __restrict__ W1, const float* __restrict__ W2,
        const float* __restrict__ W3, const float* __restrict__ b1,
        const float* __restrict__ b2,
        unsigned short* __restrict__ WAt, unsigned short* __restrict__ WBt,
        unsigned short* __restrict__ W3t, float* __restrict__ bA, float* __restrict__ bB,
        u32x4* __restrict__ outz) {
    __shared__ __align__(16) unsigned short wat[128 * 136];
    __shared__ __align__(16) unsigned short wbt[128 * 136];
    int tid = threadIdx.x, bid = blockIdx.x;
    if (bid > 0) {
        u32x4 z = (u32x4){0u, 0u, 0u, 0u};
        for (int i = (bid - 1) * 256 + tid; i < N_NODES * DIM / 4; i += OUTZ_B * 256) outz[i] = z;
        return;
    }
    // convert: wat[n][m] = bf16(Wa[m][n]), wbt[n][m] = bf16(Wb[m][n]); W3t global
    for (int idx = tid; idx < DIM * DIM; idx += 256) {
        int m = idx >> 7, n = idx & 127;
        float va = W2[m * 128 + n], vb = W2[(m + 128) * 128 + n];
        wat[n * 136 + m] = f2bf(va - vb);
        wbt[n * 136 + m] = f2bf(vb);
        W3t[n * 128 + m] = f2bf(W3[m * 128 + n]);
    }
    __syncthreads();
    // bias combine: bA[n] = b1 . Wa[:,n] + b2[n]; bB[n] = b1 . Wb[:,n]
    if (tid < 128) {
        float sA = b2[tid], sB = 0.f;
        for (int m = 0; m < 128; m++) {
            float bm = b1[m];
            sA += bm * bf2f(wat[tid * 136 + m]);
            sB += bm * bf2f(wbt[tid * 136 + m]);
        }
        bA[tid] = sA;
        bB[tid] = sB;
    }
    // WA' = W1 @ Wa, WB' = W1 @ Wb (store transposed [n][k] for node B-frags)
    int w = tid >> 6, lane = tid & 63, lr = lane & 15, q = lane >> 4;
    bf16x8 baf[2][4], bbf[2][4];
    #pragma unroll
    for (int ct = 0; ct < 2; ct++) {
        int n = (2 * w + ct) * 16 + lr;
        #pragma unroll
        for (int kt = 0; kt < 4; kt++) {
            baf[ct][kt] = __builtin_bit_cast(bf16x8, *(const u32x4*)(&wat[n * 136 + kt * 32 + q * 8]));
            bbf[ct][kt] = __builtin_bit_cast(bf16x8, *(const u32x4*)(&wbt[n * 136 + kt * 32 + q * 8]));
        }
    }
    #pragma unroll
    for (int rt = 0; rt < 8; rt++) {
        f32x4 accA[2], accB[2];
        #pragma unroll
        for (int ct = 0; ct < 2; ct++) {
            accA[ct] = (f32x4){0.f, 0.f, 0.f, 0.f};
            accB[ct] = (f32x4){0.f, 0.f, 0.f, 0.f};
        }
        #pragma unroll
        for (int kt = 0; kt < 4; kt++) {
            const float* ap = W1 + (rt * 16 + lr) * 128 + kt * 32 + q * 8;
            f32x4 x0 = *(const f32x4*)(ap);
            f32x4 x1 = *(const f32x4*)(ap + 4);
            bf16x8 a;
            #pragma unroll
            for (int j = 0; j < 4; j++) { a[j] = (__bf16)x0[j]; a[j + 4] = (__bf16)x1[j]; }
            #pragma unroll
            for (int ct = 0; ct < 2; ct++) {
                accA[ct] = __builtin_amdgcn_mfma_f32_16x16x32_bf16(a, baf[ct][kt], accA[ct], 0, 0, 0);
                accB[ct] = __builtin_amdgcn_mfma_f32_16x16x32_bf16(a, bbf[ct][kt], accB[ct], 0, 0, 0);
            }
        }
        #pragma unroll
        for (int ct = 0; ct < 2; ct++) {
            int n = (2 * w + ct) * 16 + lr;          // C/D: col(lane&15)=n, row(q*4+r)=k
            #pragma unroll
            for (int r = 0; r < 4; r++) {
                int k = rt * 16 + q * 4 + r;
                WAt[n * 128 + k] = f2bf(accA[ct][r]);
                WBt[n * 128 + k] = f2bf(accB[ct][r]);
            }
        }
    }
}

// ---- K2: blocks 0..48 = per-chunk hist (LDS, no memset needed) + exclusive scan;
//          blocks 49..830 = node GEMM: gA/gB = x @ WA'|WB' + bias, direct, no LDS.
__global__ __launch_bounds__(256, 2) void hist_node_kernel(
        const int* __restrict__ eidx, int* __restrict__ cnt, int* __restrict__ aux,
        const float* __restrict__ x,
        const unsigned short* __restrict__ WAt, const unsigned short* __restrict__ WBt,
        const float* __restrict__ bA, const float* __restrict__ bB,
        unsigned short* __restrict__ gA, unsigned short* __restrict__ gB) {
    __shared__ int lcnt[1024];
    __shared__ int sbuf[256];
    int tid = threadIdx.x, bid = blockIdx.x;
    if (bid < CHUNK_B) {
        for (int j = tid; j < 1024; j += 256) lcnt[j] = 0;
        __syncthreads();
        const int* dst = eidx + N_EDGES;
        int base = bid << 10;
        for (int e = tid; e < N_EDGES; e += 256) {       // stream full dst array (L2-shared)
            unsigned rel = (unsigned)(dst[e] - base);
            if (rel < 1024u) atomicAdd(&lcnt[rel], 1);
        }
        __syncthreads();
        int c0 = lcnt[tid * 4], c1 = lcnt[tid * 4 + 1], c2 = lcnt[tid * 4 + 2], c3 = lcnt[tid * 4 + 3];
        int s = c0 + c1 + c2 + c3;
        sbuf[tid] = s;
        __syncthreads();
        for (int off = 1; off < 256; off <<= 1) {
            int u = (tid >= off) ? sbuf[tid - off] : 0;
            __syncthreads();
            sbuf[tid] += u;
            __syncthreads();
        }
        int eb = sbuf[tid] - s;                          // exclusive within chunk
        int node = base + tid * 4;
        if (node < N_NODES)     cnt[node]     = eb;
        if (node + 1 < N_NODES) cnt[node + 1] = eb + c0;
        if (node + 2 < N_NODES) cnt[node + 2] = eb + c0 + c1;
        if (node + 3 < N_NODES) cnt[node + 3] = eb + c0 + c1 + c2;
        if (tid == 255) aux[bid] = sbuf[255];            // chunk total
        return;
    }
    // ---- node GEMM path (no LDS, no barrier)
    int bl = bid - CHUNK_B;                              // 0..781
    int w = tid >> 6, lane = tid & 63, lr = lane & 15, q = lane >> 4;
    int row0 = bl * 64 + w * 16;
    int rowA = row0 + lr; if (rowA >= N_NODES) rowA = N_NODES - 1;
    bf16x8 a[4];
    #pragma unroll
    for (int kt = 0; kt < 4; kt++) {
        const float* ap = x + (size_t)rowA * DIM + kt * 32 + q * 8;
        f32x4 x0 = *(const f32x4*)(ap);
        f32x4 x1 = *(const f32x4*)(ap + 4);
        #pragma unroll
        for (int j = 0; j < 4; j++) { a[kt][j] = (__bf16)x0[j]; a[kt][j + 4] = (__bf16)x1[j]; }
    }
    f32x4 accA[8], accB[8];
    #pragma unroll
    for (int ct = 0; ct < 8; ct++) {
        accA[ct] = (f32x4){0.f, 0.f, 0.f, 0.f};
        accB[ct] = (f32x4){0.f, 0.f, 0.f, 0.f};
    }
    #pragma unroll
    for (int ct = 0; ct < 8; ct++) {
        int n = ct * 16 + lr;
        #pragma unroll
        for (int kt = 0; kt < 4; kt++) {
            bf16x8 fa = __builtin_bit_cast(bf16x8, *(const u32x4*)(&WAt[n * 128 + kt * 32 + q * 8]));
            bf16x8 fb = __builtin_bit_cast(bf16x8, *(const u32x4*)(&WBt[n * 128 + kt * 32 + q * 8]));
            accA[ct] = __builtin_amdgcn_mfma_f32_16x16x32_bf16(a[kt], fa, accA[ct], 0, 0, 0);
            accB[ct] = __builtin_amdgcn_mfma_f32_16x16x32_bf16(a[kt], fb, accB[ct], 0, 0, 0);
        }
    }
    #pragma unroll
    for (int ct = 0; ct < 8; ct++) {
        int col = ct * 16 + lr;
        float biasA = bA[col], biasB = bB[col];
        #pragma unroll
        for (int r = 0; r < 4; r++) {                    // C/D: col=lane&15, row=quad*4+reg
            int row = row0 + q * 4 + r;
            if (row < N_NODES) {
                gA[(size_t)row * DIM + col] = f2bf(accA[ct][r] + biasA);
                gB[(size_t)row * DIM + col] = f2bf(accB[ct][r] + biasB);
            }
        }
    }
}

// ---- K3: XCD-binned scatter (set = bid&7 handles (d>>8)&7 == set): cnt atomic lines
// and spair regions stay XCD-local -> lines assemble in one L2, write back once.
__global__ __launch_bounds__(256) void scatter_kernel(
        const int* __restrict__ eidx, int* __restrict__ cursor, const int* __restrict__ aux,
        int2* __restrict__ spair) {
    __shared__ int buf[64];
    int tid = threadIdx.x, bid = blockIdx.x;
    if (tid < 64) buf[tid] = (tid < CHUNK_B) ? aux[tid] : 0;
    __syncthreads();
    if (tid == 0) {                                      // serial exclusive scan of 49
        int run = 0;
        for (int j = 0; j < CHUNK_B; j++) { int c = buf[j]; buf[j] = run; run += c; }
    }
    __syncthreads();
    int set = bid & 7;
    int j = bid >> 3;
    for (int e = j * 256 + tid; e < N_EDGES; e += (SCAT_B / 8) * 256) {
        int d = eidx[N_EDGES + e];
        if (((d >> 8) & 7) == set) {
            int s = eidx[e];
            int p = atomicAdd(&cursor[d], 1) + buf[d >> 10];
            spair[p] = make_int2(s, d);
        }
    }
}

// ---- K4: edge = relu(gA[dst]+gB[src]) -> GEMM2 -> segmented scatter-max (R12 verbatim)
__global__ __launch_bounds__(256, 4) void edge_kernel(
        const unsigned short* __restrict__ gA,
        const unsigned short* __restrict__ gB,
        const int2* __restrict__ spair,
        const unsigned short* __restrict__ W3t,
        const float* __restrict__ b3,
        unsigned int* __restrict__ out) {
    __shared__ __align__(16) unsigned short m1_lds[64 * 136];
    __shared__ __align__(16) unsigned short m2_lds[64 * 136];
    __shared__ int s_dst[2][64];

    int tid = threadIdx.x;
    int w = tid >> 6, lane = tid & 63;
    int lr = lane & 15, q = lane >> 4;
    int tr = tid >> 4;
    int c = (tid & 15) * 8;

    bf16x8 b3f[2][4];
    float b3v[2];
    #pragma unroll
    for (int ct = 0; ct < 2; ct++) {
        int n = (2 * w + ct) * 16 + lr;
        #pragma unroll
        for (int kt = 0; kt < 4; kt++)
            b3f[ct][kt] = __builtin_bit_cast(bf16x8, *(const u32x4*)(&W3t[n * 128 + kt * 32 + q * 8]));
        b3v[ct] = b3[n];
    }

    int tb = blockIdx.x;
    int sel = 0;
    int2 pr[4];
    {
        int eb = tb * 64;
        #pragma unroll
        for (int it = 0; it < 4; it++) pr[it] = spair[eb + tr + 16 * it];
    }

    for (; tb < NTILES; tb += gridDim.x) {
        #pragma unroll
        for (int it = 0; it < 4; it++) {
            int t = tr + 16 * it;
            u32x4 ga = *(const u32x4*)(&gA[(size_t)pr[it].y * DIM + c]);
            u32x4 gb = *(const u32x4*)(&gB[(size_t)pr[it].x * DIM + c]);
            u32x4 m;
            #pragma unroll
            for (int jj = 0; jj < 4; jj++) {
                float lo = __uint_as_float(ga[jj] << 16) + __uint_as_float(gb[jj] << 16);
                float hi = __uint_as_float(ga[jj] & 0xffff0000u) + __uint_as_float(gb[jj] & 0xffff0000u);
                m[jj] = pack_bf2(fmaxf(lo, 0.f), fmaxf(hi, 0.f));
            }
            *(u32x4*)(&m1_lds[t * 136 + c]) = m;
        }
        if ((tid & 15) == 0) {
            #pragma unroll
            for (int it = 0; it < 4; it++) s_dst[sel][tr + 16 * it] = pr[it].y;
        }
        __syncthreads();   // (1) m1 ready; also orders segmax(t-1) before m2 writes(t)

        int nx = tb + (int)gridDim.x;
        int2 npr[4];
        if (nx < NTILES) {
            int eb = nx * 64;
            #pragma unroll
            for (int it = 0; it < 4; it++) npr[it] = spair[eb + tr + 16 * it];
        }

        f32x4 acc2[4][2];
        #pragma unroll
        for (int rt = 0; rt < 4; rt++)
            #pragma unroll
            for (int ct = 0; ct < 2; ct++) acc2[rt][ct] = (f32x4){0.f, 0.f, 0.f, 0.f};
        #pragma unroll
        for (int kt = 0; kt < 4; kt++) {
            #pragma unroll
            for (int rt = 0; rt < 4; rt++) {
                bf16x8 a = __builtin_bit_cast(bf16x8,
                    *(const u32x4*)(&m1_lds[(rt * 16 + lr) * 136 + kt * 32 + q * 8]));
                acc2[rt][0] = __builtin_amdgcn_mfma_f32_16x16x32_bf16(a, b3f[0][kt], acc2[rt][0], 0, 0, 0);
                acc2[rt][1] = __builtin_amdgcn_mfma_f32_16x16x32_bf16(a, b3f[1][kt], acc2[rt][1], 0, 0, 0);
            }
        }
        #pragma unroll
        for (int rt = 0; rt < 4; rt++) {
            #pragma unroll
            for (int ct = 0; ct < 2; ct++) {
                int col = (2 * w + ct) * 16 + lr;
                #pragma unroll
                for (int r = 0; r < 4; r++)
                    m2_lds[(rt * 16 + q * 4 + r) * 136 + col] = f2bf_hw(fmaxf(acc2[rt][ct][r] + b3v[ct], 0.f));
            }
        }
        __syncthreads();   // (2) m2 ready

        {
            int col = tid & 127;
            int r0 = (tid >> 7) * 32;
            float cur = bf2f(m2_lds[r0 * 136 + col]);
            int d = s_dst[sel][r0];
            #pragma unroll 4
            for (int i = 1; i < 32; i++) {
                int dn = s_dst[sel][r0 + i];
                float v = bf2f(m2_lds[(r0 + i) * 136 + col]);
                if (dn != d) {
                    atomicMax(&out[(size_t)d * DIM + col], __float_as_uint(cur));
                    d = dn; cur = v;
                } else {
                    cur = fmaxf(cur, v);
                }
            }
            atomicMax(&out[(size_t)d * DIM + col], __float_as_uint(cur));
        }

        sel ^= 1;
        #pragma unroll
        for (int it = 0; it < 4; it++) pr[it] = npr[it];
    }
}

extern "C" void kernel_launch(void* const* d_in, const int* in_sizes, int n_in,
                              void* d_out, int out_size, void* d_ws, size_t ws_size,
                              hipStream_t stream) {
    const float* x  = (const float*)d_in[0];
    const int* eidx = (const int*)d_in[1];
    const float* W1 = (const float*)d_in[2];
    const float* b1 = (const float*)d_in[3];
    const float* W2 = (const float*)d_in[4];
    const float* b2 = (const float*)d_in[5];
    const float* W3 = (const float*)d_in[6];
    const float* b3 = (const float*)d_in[7];

    char* ws = (char*)d_ws;
    unsigned short* gA  = (unsigned short*)ws;                     // 12,800,000 B
    unsigned short* gB  = (unsigned short*)(ws + 12800000);        // 12,800,000 B
    unsigned short* WAt = (unsigned short*)(ws + 25600000);        // 32,768 B
    unsigned short* WBt = (unsigned short*)(ws + 25632768);        // 32,768 B
    unsigned short* W3t = (unsigned short*)(ws + 25665536);        // 32,768 B
    float* bA           = (float*)(ws + 25698304);                 // 512 B
    float* bB           = (float*)(ws + 25698816);                 // 512 B
    int* cnt            = (int*)(ws + 25699328);                   // 200,000 B
    int* aux            = (int*)(ws + 25899328);                   // 256 B
    int2* spair         = (int2*)(ws + 25899584);                  // 6,400,000 B -> 32,299,584 total

    prep_kernel<<<1 + OUTZ_B, 256, 0, stream>>>(W1, W2, W3, b1, b2,
        WAt, WBt, W3t, bA, bB, (u32x4*)d_out);
    hist_node_kernel<<<CHUNK_B + NODE_B, 256, 0, stream>>>(eidx, cnt, aux,
        x, WAt, WBt, bA, bB, gA, gB);
    scatter_kernel<<<SCAT_B, 256, 0, stream>>>(eidx, cnt, aux, spair);
    edge_kernel<<<2048, 256, 0, stream>>>(gA, gB, spair, W3t, b3, (unsigned int*)d_out);
}

// Round 14
// 295.288 us; speedup vs baseline: 3.8781x; 3.8781x over previous
//
#include <hip/hip_runtime.h>
#include <hip/hip_bf16.h>

#define N_NODES 50000
#define N_EDGES 800000
#define DIM 128
#define NTILES (N_EDGES / 64)   // 12500 exactly
#define SCAN_B 196              // ceil(50000/256)
#define HIST_B 3125             // 800000/256
#define NODE_B 782              // ceil(50000/64)
#define OUTZ_B 512
#define SCAT_B 2048             // 8 sets x 256 blocks; set = bid&7 -> XCD heuristic

typedef __bf16 bf16x8 __attribute__((ext_vector_type(8)));
typedef float f32x4 __attribute__((ext_vector_type(4)));
typedef unsigned int u32x4 __attribute__((ext_vector_type(4)));

__device__ __forceinline__ unsigned short f2bf(float f) {
    unsigned u = __float_as_uint(f);
    u += 0x7fffu + ((u >> 16) & 1u);          // round-to-nearest-even
    return (unsigned short)(u >> 16);
}
__device__ __forceinline__ float bf2f(unsigned short s) {
    return __uint_as_float(((unsigned)s) << 16);
}
// hw-packed f32x2 -> bf16x2 (v_cvt_pk_bf16_f32 on gfx950), lo in low 16 bits
__device__ __forceinline__ unsigned pack_bf2(float lo, float hi) {
    __hip_bfloat162 h = __float22bfloat162_rn(make_float2(lo, hi));
    unsigned u;
    __builtin_memcpy(&u, &h, 4);
    return u;
}
__device__ __forceinline__ unsigned short f2bf_hw(float f) {
    __hip_bfloat16 h = __float2bfloat16(f);
    unsigned short s;
    __builtin_memcpy(&s, &h, 2);
    return s;
}

// ---- K1: block 0 = weight combine; blocks 1..3125 = dst hist (global atomics,
// 800K total — device-wide this is a few µs, R12-proven); rest = zero out.
// lin1 is LINEAR (no relu): gA = x@(W1@Wa) + (b1@Wa + b2), gB = x@(W1@Wb) + b1@Wb
// where Wa = W2a - W2b, Wb = W2b. Precompute WA'=W1@Wa, WB'=W1@Wb (bf16 MFMA).
__global__ void prep_kernel(
        const float* __restrict__ W1, const float* __restrict__ W2,
        const float* __restrict__ W3, const float* __restrict__ b1,
        const float* __restrict__ b2, const int* __restrict__ eidx,
        unsigned short* __restrict__ WAt, unsigned short* __restrict__ WBt,
        unsigned short* __restrict__ W3t, float* __restrict__ bA, float* __restrict__ bB,
        int* __restrict__ cnt, u32x4* __restrict__ outz) {
    __shared__ __align__(16) unsigned short wat[128 * 136];
    __shared__ __align__(16) unsigned short wbt[128 * 136];
    int tid = threadIdx.x, bid = blockIdx.x;
    if (bid >= 1 && bid <= HIST_B) {
        int e = (bid - 1) * 256 + tid;        // exactly covers 800000
        atomicAdd(&cnt[eidx[N_EDGES + e]], 1);
        return;
    }
    if (bid > HIST_B) {
        int b = bid - 1 - HIST_B;
        u32x4 z = (u32x4){0u, 0u, 0u, 0u};
        for (int i = b * 256 + tid; i < N_NODES * DIM / 4; i += OUTZ_B * 256) outz[i] = z;
        return;
    }
    // ---- block 0: weight combine
    for (int idx = tid; idx < DIM * DIM; idx += 256) {
        int m = idx >> 7, n = idx & 127;
        float va = W2[m * 128 + n], vb = W2[(m + 128) * 128 + n];
        wat[n * 136 + m] = f2bf(va - vb);
        wbt[n * 136 + m] = f2bf(vb);
        W3t[n * 128 + m] = f2bf(W3[m * 128 + n]);
    }
    __syncthreads();
    // bias combine: bA[n] = b1 . Wa[:,n] + b2[n]; bB[n] = b1 . Wb[:,n]
    if (tid < 128) {
        float sA = b2[tid], sB = 0.f;
        for (int m = 0; m < 128; m++) {
            float bm = b1[m];
            sA += bm * bf2f(wat[tid * 136 + m]);
            sB += bm * bf2f(wbt[tid * 136 + m]);
        }
        bA[tid] = sA;
        bB[tid] = sB;
    }
    // WA' = W1 @ Wa, WB' = W1 @ Wb (store transposed [n][k] for node B-frags)
    int w = tid >> 6, lane = tid & 63, lr = lane & 15, q = lane >> 4;
    bf16x8 baf[2][4], bbf[2][4];
    #pragma unroll
    for (int ct = 0; ct < 2; ct++) {
        int n = (2 * w + ct) * 16 + lr;
        #pragma unroll
        for (int kt = 0; kt < 4; kt++) {
            baf[ct][kt] = __builtin_bit_cast(bf16x8, *(const u32x4*)(&wat[n * 136 + kt * 32 + q * 8]));
            bbf[ct][kt] = __builtin_bit_cast(bf16x8, *(const u32x4*)(&wbt[n * 136 + kt * 32 + q * 8]));
        }
    }
    #pragma unroll
    for (int rt = 0; rt < 8; rt++) {
        f32x4 accA[2], accB[2];
        #pragma unroll
        for (int ct = 0; ct < 2; ct++) {
            accA[ct] = (f32x4){0.f, 0.f, 0.f, 0.f};
            accB[ct] = (f32x4){0.f, 0.f, 0.f, 0.f};
        }
        #pragma unroll
        for (int kt = 0; kt < 4; kt++) {
            const float* ap = W1 + (rt * 16 + lr) * 128 + kt * 32 + q * 8;
            f32x4 x0 = *(const f32x4*)(ap);
            f32x4 x1 = *(const f32x4*)(ap + 4);
            bf16x8 a;
            #pragma unroll
            for (int j = 0; j < 4; j++) { a[j] = (__bf16)x0[j]; a[j + 4] = (__bf16)x1[j]; }
            #pragma unroll
            for (int ct = 0; ct < 2; ct++) {
                accA[ct] = __builtin_amdgcn_mfma_f32_16x16x32_bf16(a, baf[ct][kt], accA[ct], 0, 0, 0);
                accB[ct] = __builtin_amdgcn_mfma_f32_16x16x32_bf16(a, bbf[ct][kt], accB[ct], 0, 0, 0);
            }
        }
        #pragma unroll
        for (int ct = 0; ct < 2; ct++) {
            int n = (2 * w + ct) * 16 + lr;          // C/D: col(lane&15)=n, row(q*4+r)=k
            #pragma unroll
            for (int r = 0; r < 4; r++) {
                int k = rt * 16 + q * 4 + r;
                WAt[n * 128 + k] = f2bf(accA[ct][r]);
                WBt[n * 128 + k] = f2bf(accB[ct][r]);
            }
        }
    }
}

// ---- K2: blocks 0..195 = per-chunk exclusive scan of cnt; blocks 196.. = node GEMM
// (direct, no LDS: gA/gB = x @ WA'|WB' + bias).
__global__ __launch_bounds__(256, 2) void scan_node_kernel(
        int* __restrict__ cnt, int* __restrict__ aux,
        const float* __restrict__ x,
        const unsigned short* __restrict__ WAt, const unsigned short* __restrict__ WBt,
        const float* __restrict__ bA, const float* __restrict__ bB,
        unsigned short* __restrict__ gA, unsigned short* __restrict__ gB) {
    __shared__ int sbuf[256];
    int tid = threadIdx.x, bid = blockIdx.x;
    if (bid < SCAN_B) {
        int i = bid * 256 + tid;
        int v = (i < N_NODES) ? cnt[i] : 0;
        sbuf[tid] = v;
        __syncthreads();
        for (int off = 1; off < 256; off <<= 1) {
            int u = (tid >= off) ? sbuf[tid - off] : 0;
            __syncthreads();
            sbuf[tid] += u;
            __syncthreads();
        }
        if (i < N_NODES) cnt[i] = sbuf[tid] - v;         // exclusive within chunk
        if (tid == 255) aux[bid] = sbuf[255];            // chunk total
        return;
    }
    // ---- node GEMM path (no LDS, no barrier)
    int bl = bid - SCAN_B;                               // 0..781
    int w = tid >> 6, lane = tid & 63, lr = lane & 15, q = lane >> 4;
    int row0 = bl * 64 + w * 16;
    int rowA = row0 + lr; if (rowA >= N_NODES) rowA = N_NODES - 1;
    bf16x8 a[4];
    #pragma unroll
    for (int kt = 0; kt < 4; kt++) {
        const float* ap = x + (size_t)rowA * DIM + kt * 32 + q * 8;
        f32x4 x0 = *(const f32x4*)(ap);
        f32x4 x1 = *(const f32x4*)(ap + 4);
        #pragma unroll
        for (int j = 0; j < 4; j++) { a[kt][j] = (__bf16)x0[j]; a[kt][j + 4] = (__bf16)x1[j]; }
    }
    f32x4 accA[8], accB[8];
    #pragma unroll
    for (int ct = 0; ct < 8; ct++) {
        accA[ct] = (f32x4){0.f, 0.f, 0.f, 0.f};
        accB[ct] = (f32x4){0.f, 0.f, 0.f, 0.f};
    }
    #pragma unroll
    for (int ct = 0; ct < 8; ct++) {
        int n = ct * 16 + lr;
        #pragma unroll
        for (int kt = 0; kt < 4; kt++) {
            bf16x8 fa = __builtin_bit_cast(bf16x8, *(const u32x4*)(&WAt[n * 128 + kt * 32 + q * 8]));
            bf16x8 fb = __builtin_bit_cast(bf16x8, *(const u32x4*)(&WBt[n * 128 + kt * 32 + q * 8]));
            accA[ct] = __builtin_amdgcn_mfma_f32_16x16x32_bf16(a[kt], fa, accA[ct], 0, 0, 0);
            accB[ct] = __builtin_amdgcn_mfma_f32_16x16x32_bf16(a[kt], fb, accB[ct], 0, 0, 0);
        }
    }
    #pragma unroll
    for (int ct = 0; ct < 8; ct++) {
        int col = ct * 16 + lr;
        float biasA = bA[col], biasB = bB[col];
        #pragma unroll
        for (int r = 0; r < 4; r++) {                    // C/D: col=lane&15, row=quad*4+reg
            int row = row0 + q * 4 + r;
            if (row < N_NODES) {
                gA[(size_t)row * DIM + col] = f2bf(accA[ct][r] + biasA);
                gB[(size_t)row * DIM + col] = f2bf(accB[ct][r] + biasB);
            }
        }
    }
}

// ---- K3: XCD-binned scatter (set = bid&7 handles (d>>8)&7 == set): cnt atomic lines
// and spair regions stay XCD-local -> lines assemble in one L2, write back once.
__global__ __launch_bounds__(256) void scatter_kernel(
        const int* __restrict__ eidx, int* __restrict__ cursor, const int* __restrict__ aux,
        int2* __restrict__ spair) {
    __shared__ int buf[256];
    int tid = threadIdx.x, bid = blockIdx.x;
    int v = (tid < SCAN_B) ? aux[tid] : 0;
    buf[tid] = v;
    __syncthreads();
    for (int off = 1; off < 256; off <<= 1) {
        int u = (tid >= off) ? buf[tid - off] : 0;
        __syncthreads();
        buf[tid] += u;
        __syncthreads();
    }
    int excl = buf[tid] - v;
    __syncthreads();
    buf[tid] = excl;
    __syncthreads();
    int set = bid & 7;
    int j = bid >> 3;
    for (int e = j * 256 + tid; e < N_EDGES; e += (SCAT_B / 8) * 256) {
        int d = eidx[N_EDGES + e];
        if (((d >> 8) & 7) == set) {
            int s = eidx[e];
            int p = atomicAdd(&cursor[d], 1) + buf[d >> 8];
            spair[p] = make_int2(s, d);
        }
    }
}

// ---- K4: edge = relu(gA[dst]+gB[src]) -> GEMM2 -> segmented scatter-max (R12 verbatim)
__global__ __launch_bounds__(256, 4) void edge_kernel(
        const unsigned short* __restrict__ gA,
        const unsigned short* __restrict__ gB,
        const int2* __restrict__ spair,
        const unsigned short* __restrict__ W3t,
        const float* __restrict__ b3,
        unsigned int* __restrict__ out) {
    __shared__ __align__(16) unsigned short m1_lds[64 * 136];
    __shared__ __align__(16) unsigned short m2_lds[64 * 136];
    __shared__ int s_dst[2][64];

    int tid = threadIdx.x;
    int w = tid >> 6, lane = tid & 63;
    int lr = lane & 15, q = lane >> 4;
    int tr = tid >> 4;
    int c = (tid & 15) * 8;

    bf16x8 b3f[2][4];
    float b3v[2];
    #pragma unroll
    for (int ct = 0; ct < 2; ct++) {
        int n = (2 * w + ct) * 16 + lr;
        #pragma unroll
        for (int kt = 0; kt < 4; kt++)
            b3f[ct][kt] = __builtin_bit_cast(bf16x8, *(const u32x4*)(&W3t[n * 128 + kt * 32 + q * 8]));
        b3v[ct] = b3[n];
    }

    int tb = blockIdx.x;
    int sel = 0;
    int2 pr[4];
    {
        int eb = tb * 64;
        #pragma unroll
        for (int it = 0; it < 4; it++) pr[it] = spair[eb + tr + 16 * it];
    }

    for (; tb < NTILES; tb += gridDim.x) {
        #pragma unroll
        for (int it = 0; it < 4; it++) {
            int t = tr + 16 * it;
            u32x4 ga = *(const u32x4*)(&gA[(size_t)pr[it].y * DIM + c]);
            u32x4 gb = *(const u32x4*)(&gB[(size_t)pr[it].x * DIM + c]);
            u32x4 m;
            #pragma unroll
            for (int jj = 0; jj < 4; jj++) {
                float lo = __uint_as_float(ga[jj] << 16) + __uint_as_float(gb[jj] << 16);
                float hi = __uint_as_float(ga[jj] & 0xffff0000u) + __uint_as_float(gb[jj] & 0xffff0000u);
                m[jj] = pack_bf2(fmaxf(lo, 0.f), fmaxf(hi, 0.f));
            }
            *(u32x4*)(&m1_lds[t * 136 + c]) = m;
        }
        if ((tid & 15) == 0) {
            #pragma unroll
            for (int it = 0; it < 4; it++) s_dst[sel][tr + 16 * it] = pr[it].y;
        }
        __syncthreads();   // (1) m1 ready; also orders segmax(t-1) before m2 writes(t)

        int nx = tb + (int)gridDim.x;
        int2 npr[4];
        if (nx < NTILES) {
            int eb = nx * 64;
            #pragma unroll
            for (int it = 0; it < 4; it++) npr[it] = spair[eb + tr + 16 * it];
        }

        f32x4 acc2[4][2];
        #pragma unroll
        for (int rt = 0; rt < 4; rt++)
            #pragma unroll
            for (int ct = 0; ct < 2; ct++) acc2[rt][ct] = (f32x4){0.f, 0.f, 0.f, 0.f};
        #pragma unroll
        for (int kt = 0; kt < 4; kt++) {
            #pragma unroll
            for (int rt = 0; rt < 4; rt++) {
                bf16x8 a = __builtin_bit_cast(bf16x8,
                    *(const u32x4*)(&m1_lds[(rt * 16 + lr) * 136 + kt * 32 + q * 8]));
                acc2[rt][0] = __builtin_amdgcn_mfma_f32_16x16x32_bf16(a, b3f[0][kt], acc2[rt][0], 0, 0, 0);
                acc2[rt][1] = __builtin_amdgcn_mfma_f32_16x16x32_bf16(a, b3f[1][kt], acc2[rt][1], 0, 0, 0);
            }
        }
        #pragma unroll
        for (int rt = 0; rt < 4; rt++) {
            #pragma unroll
            for (int ct = 0; ct < 2; ct++) {
                int col = (2 * w + ct) * 16 + lr;
                #pragma unroll
                for (int r = 0; r < 4; r++)
                    m2_lds[(rt * 16 + q * 4 + r) * 136 + col] = f2bf_hw(fmaxf(acc2[rt][ct][r] + b3v[ct], 0.f));
            }
        }
        __syncthreads();   // (2) m2 ready

        {
            int col = tid & 127;
            int r0 = (tid >> 7) * 32;
            float cur = bf2f(m2_lds[r0 * 136 + col]);
            int d = s_dst[sel][r0];
            #pragma unroll 4
            for (int i = 1; i < 32; i++) {
                int dn = s_dst[sel][r0 + i];
                float v = bf2f(m2_lds[(r0 + i) * 136 + col]);
                if (dn != d) {
                    atomicMax(&out[(size_t)d * DIM + col], __float_as_uint(cur));
                    d = dn; cur = v;
                } else {
                    cur = fmaxf(cur, v);
                }
            }
            atomicMax(&out[(size_t)d * DIM + col], __float_as_uint(cur));
        }

        sel ^= 1;
        #pragma unroll
        for (int it = 0; it < 4; it++) pr[it] = npr[it];
    }
}

extern "C" void kernel_launch(void* const* d_in, const int* in_sizes, int n_in,
                              void* d_out, int out_size, void* d_ws, size_t ws_size,
                              hipStream_t stream) {
    const float* x  = (const float*)d_in[0];
    const int* eidx = (const int*)d_in[1];
    const float* W1 = (const float*)d_in[2];
    const float* b1 = (const float*)d_in[3];
    const float* W2 = (const float*)d_in[4];
    const float* b2 = (const float*)d_in[5];
    const float* W3 = (const float*)d_in[6];
    const float* b3 = (const float*)d_in[7];

    char* ws = (char*)d_ws;
    unsigned short* gA  = (unsigned short*)ws;                     // 12,800,000 B
    unsigned short* gB  = (unsigned short*)(ws + 12800000);        // 12,800,000 B
    unsigned short* WAt = (unsigned short*)(ws + 25600000);        // 32,768 B
    unsigned short* WBt = (unsigned short*)(ws + 25632768);        // 32,768 B
    unsigned short* W3t = (unsigned short*)(ws + 25665536);        // 32,768 B
    float* bA           = (float*)(ws + 25698304);                 // 512 B
    float* bB           = (float*)(ws + 25698816);                 // 512 B
    int* cnt            = (int*)(ws + 25699328);                   // 200,000 B
    int* aux            = (int*)(ws + 25899328);                   // 1,024 B
    int2* spair         = (int2*)(ws + 25900352);                  // 6,400,000 B -> 32,300,352 total

    (void)hipMemsetAsync(cnt, 0, N_NODES * sizeof(int), stream);
    prep_kernel<<<1 + HIST_B + OUTZ_B, 256, 0, stream>>>(W1, W2, W3, b1, b2, eidx,
        WAt, WBt, W3t, bA, bB, cnt, (u32x4*)d_out);
    scan_node_kernel<<<SCAN_B + NODE_B, 256, 0, stream>>>(cnt, aux,
        x, WAt, WBt, bA, bB, gA, gB);
    scatter_kernel<<<SCAT_B, 256, 0, stream>>>(eidx, cnt, aux, spair);
    edge_kernel<<<2048, 256, 0, stream>>>(gA, gB, spair, W3t, b3, (unsigned int*)d_out);
}

// Round 15
// 272.564 us; speedup vs baseline: 4.2014x; 1.0834x over previous
//
#include <hip/hip_runtime.h>
#include <hip/hip_bf16.h>

#define N_NODES 50000
#define N_EDGES 800000
#define DIM 128
#define NTILES (N_EDGES / 64)   // 12500 exactly
#define SCAN_B 196              // ceil(50000/256)
#define HIST_B 3125             // 800000/256
#define NODE_B 782              // ceil(50000/64)
#define OUTZ_B 512
#define SCAT_B 2048             // 8 sets x 256 blocks; set = bid&7 -> XCD heuristic

typedef __bf16 bf16x8 __attribute__((ext_vector_type(8)));
typedef float f32x4 __attribute__((ext_vector_type(4)));
typedef unsigned int u32x4 __attribute__((ext_vector_type(4)));
typedef short s16x2 __attribute__((ext_vector_type(2)));

__device__ __forceinline__ unsigned short f2bf(float f) {
    unsigned u = __float_as_uint(f);
    u += 0x7fffu + ((u >> 16) & 1u);          // round-to-nearest-even
    return (unsigned short)(u >> 16);
}
__device__ __forceinline__ float bf2f(unsigned short s) {
    return __uint_as_float(((unsigned)s) << 16);
}
// hw-packed f32x2 -> bf16x2 (v_cvt_pk_bf16_f32 on gfx950), lo in low 16 bits
__device__ __forceinline__ unsigned pack_bf2(float lo, float hi) {
    __hip_bfloat162 h = __float22bfloat162_rn(make_float2(lo, hi));
    unsigned u;
    __builtin_memcpy(&u, &h, 4);
    return u;
}
__device__ __forceinline__ unsigned short f2bf_hw(float f) {
    __hip_bfloat16 h = __float2bfloat16(f);
    unsigned short s;
    __builtin_memcpy(&s, &h, 2);
    return s;
}

// ---- K1 (R12-proven): convert weights (blocks 0..255) + dst hist (256..3380) + zero out
// identity: [h_i, h_j-h_i] @ W2 = h_i @ (W2a - W2b) + h_j @ W2b
__global__ void prep_kernel(const float* __restrict__ W1, const float* __restrict__ W2,
                            const float* __restrict__ W3, const int* __restrict__ eidx,
                            unsigned short* __restrict__ W1t, unsigned short* __restrict__ Wat,
                            unsigned short* __restrict__ Wbt, unsigned short* __restrict__ W3t,
                            int* __restrict__ cnt, u32x4* __restrict__ outz) {
    int bid = blockIdx.x, tid = threadIdx.x;
    if (bid < 256) {
        int i = bid * 256 + tid;
        int j = i & (DIM * DIM - 1);
        int k = j >> 7, n = j & 127;
        int sec = i >> 14;
        if (sec == 0)      W1t[n * 128 + k] = f2bf(W1[k * 128 + n]);
        else if (sec == 1) Wat[n * 128 + k] = f2bf(W2[k * 128 + n] - W2[(k + 128) * 128 + n]);
        else if (sec == 2) Wbt[n * 128 + k] = f2bf(W2[(k + 128) * 128 + n]);
        else               W3t[n * 128 + k] = f2bf(W3[k * 128 + n]);
    } else if (bid < 256 + HIST_B) {
        int e = (bid - 256) * 256 + tid;      // exactly covers 800000
        atomicAdd(&cnt[eidx[N_EDGES + e]], 1);
    } else {
        int b = bid - 256 - HIST_B;
        u32x4 z = (u32x4){0u, 0u, 0u, 0u};
        for (int i = b * 256 + tid; i < N_NODES * DIM / 4; i += OUTZ_B * 256) outz[i] = z;
    }
}

// ---- K2 (R12-proven): scanA (blocks 0..195) + node GEMMs (blocks 196..977)
// node: h = bf16(x@W1+b1) -> LDS -> gA = bf16(h@Wa + b2), gB = bf16(h@Wb)
__global__ __launch_bounds__(256, 2) void scan_node_kernel(
        int* __restrict__ cnt, int* __restrict__ aux,
        const float* __restrict__ x, const unsigned short* __restrict__ W1t,
        const unsigned short* __restrict__ Wat, const unsigned short* __restrict__ Wbt,
        const float* __restrict__ b1, const float* __restrict__ b2,
        unsigned short* __restrict__ gA, unsigned short* __restrict__ gB) {
    __shared__ __align__(16) unsigned short w1t[128 * 136];   // head doubles as scan buf
    __shared__ __align__(16) unsigned short h_lds[64 * 136];
    int tid = threadIdx.x, bid = blockIdx.x;
    if (bid < SCAN_B) {
        int* buf = (int*)w1t;
        int i = bid * 256 + tid;
        int v = (i < N_NODES) ? cnt[i] : 0;
        buf[tid] = v;
        __syncthreads();
        for (int off = 1; off < 256; off <<= 1) {
            int u = (tid >= off) ? buf[tid - off] : 0;
            __syncthreads();
            buf[tid] += u;
            __syncthreads();
        }
        if (i < N_NODES) cnt[i] = buf[tid] - v;
        if (tid == 255) aux[bid] = buf[255];
        return;
    }
    int bl = bid - SCAN_B;
    #pragma unroll
    for (int it = 0; it < 8; it++) {
        int idx = (tid + it * 256) * 8;
        int n = idx >> 7, k = idx & 127;
        *(u32x4*)(&w1t[n * 136 + k]) = *(const u32x4*)(&W1t[idx]);
    }
    int w = tid >> 6, lane = tid & 63;
    int lr = lane & 15, q = lane >> 4;
    bf16x8 baf[2][4], bbf[2][4];
    float b2v[2];
    #pragma unroll
    for (int ct = 0; ct < 2; ct++) {
        int n = (2 * w + ct) * 16 + lr;
        #pragma unroll
        for (int kt = 0; kt < 4; kt++) {
            baf[ct][kt] = __builtin_bit_cast(bf16x8, *(const u32x4*)(&Wat[n * 128 + kt * 32 + q * 8]));
            bbf[ct][kt] = __builtin_bit_cast(bf16x8, *(const u32x4*)(&Wbt[n * 128 + kt * 32 + q * 8]));
        }
        b2v[ct] = b2[n];
    }
    __syncthreads();
    int row0 = bl * 64;
    int rowA = row0 + w * 16 + lr; if (rowA >= N_NODES) rowA = N_NODES - 1;
    {
        f32x4 acc[8];
        #pragma unroll
        for (int ct = 0; ct < 8; ct++) acc[ct] = (f32x4){0.f, 0.f, 0.f, 0.f};
        #pragma unroll
        for (int kt = 0; kt < 4; kt++) {
            const float* ap = x + (size_t)rowA * DIM + kt * 32 + q * 8;
            f32x4 x0 = *(const f32x4*)(ap);
            f32x4 x1 = *(const f32x4*)(ap + 4);
            bf16x8 a;
            #pragma unroll
            for (int j = 0; j < 4; j++) { a[j] = (__bf16)x0[j]; a[j + 4] = (__bf16)x1[j]; }
            #pragma unroll
            for (int ct = 0; ct < 8; ct++) {
                bf16x8 b = __builtin_bit_cast(bf16x8,
                    *(const u32x4*)(&w1t[(ct * 16 + lr) * 136 + kt * 32 + q * 8]));
                acc[ct] = __builtin_amdgcn_mfma_f32_16x16x32_bf16(a, b, acc[ct], 0, 0, 0);
            }
        }
        #pragma unroll
        for (int ct = 0; ct < 8; ct++) {
            int col = ct * 16 + lr;
            float bias = b1[col];
            #pragma unroll
            for (int r = 0; r < 4; r++)   // C/D: col=lane&15, row=quad*4+reg
                h_lds[(w * 16 + q * 4 + r) * 136 + col] = f2bf(acc[ct][r] + bias);
        }
    }
    __syncthreads();
    {
        f32x4 accA[4][2], accB[4][2];
        #pragma unroll
        for (int rt = 0; rt < 4; rt++)
            #pragma unroll
            for (int ct = 0; ct < 2; ct++) {
                accA[rt][ct] = (f32x4){0.f, 0.f, 0.f, 0.f};
                accB[rt][ct] = (f32x4){0.f, 0.f, 0.f, 0.f};
            }
        #pragma unroll
        for (int kt = 0; kt < 4; kt++) {
            #pragma unroll
            for (int rt = 0; rt < 4; rt++) {
                bf16x8 a = __builtin_bit_cast(bf16x8,
                    *(const u32x4*)(&h_lds[(rt * 16 + lr) * 136 + kt * 32 + q * 8]));
                accA[rt][0] = __builtin_amdgcn_mfma_f32_16x16x32_bf16(a, baf[0][kt], accA[rt][0], 0, 0, 0);
                accA[rt][1] = __builtin_amdgcn_mfma_f32_16x16x32_bf16(a, baf[1][kt], accA[rt][1], 0, 0, 0);
                accB[rt][0] = __builtin_amdgcn_mfma_f32_16x16x32_bf16(a, bbf[0][kt], accB[rt][0], 0, 0, 0);
                accB[rt][1] = __builtin_amdgcn_mfma_f32_16x16x32_bf16(a, bbf[1][kt], accB[rt][1], 0, 0, 0);
            }
        }
        #pragma unroll
        for (int rt = 0; rt < 4; rt++) {
            #pragma unroll
            for (int ct = 0; ct < 2; ct++) {
                int col = (2 * w + ct) * 16 + lr;
                #pragma unroll
                for (int r = 0; r < 4; r++) {
                    int row = row0 + rt * 16 + q * 4 + r;
                    if (row < N_NODES) {
                        gA[(size_t)row * DIM + col] = f2bf(accA[rt][ct][r] + b2v[ct]);
                        gB[(size_t)row * DIM + col] = f2bf(accB[rt][ct][r]);
                    }
                }
            }
        }
    }
}

// ---- K3 (R12-proven): XCD-binned scatter
__global__ __launch_bounds__(256) void scatter_kernel(
        const int* __restrict__ eidx, int* __restrict__ cursor, const int* __restrict__ aux,
        int2* __restrict__ spair) {
    __shared__ int buf[256];
    int tid = threadIdx.x, bid = blockIdx.x;
    int v = (tid < SCAN_B) ? aux[tid] : 0;
    buf[tid] = v;
    __syncthreads();
    for (int off = 1; off < 256; off <<= 1) {
        int u = (tid >= off) ? buf[tid - off] : 0;
        __syncthreads();
        buf[tid] += u;
        __syncthreads();
    }
    int excl = buf[tid] - v;
    __syncthreads();
    buf[tid] = excl;
    __syncthreads();
    int set = bid & 7;
    int j = bid >> 3;
    for (int e = j * 256 + tid; e < N_EDGES; e += (SCAT_B / 8) * 256) {
        int d = eidx[N_EDGES + e];
        if (((d >> 8) & 7) == set) {
            int s = eidx[e];
            int p = atomicAdd(&cursor[d], 1) + buf[d >> 8];
            spair[p] = make_int2(s, d);
        }
    }
}

// ---- K4: edge = relu(gA[dst]+gB[src]) -> GEMM2 -> segmented scatter-max.
// segmax: packed s16x2 max (bf16 >= 0 post-relu -> int16 compare == float compare),
// 4 row-groups of 16 (group == wave -> run-boundary branch wave-uniform), 2 cols/thread.
__global__ __launch_bounds__(256, 4) void edge_kernel(
        const unsigned short* __restrict__ gA,
        const unsigned short* __restrict__ gB,
        const int2* __restrict__ spair,
        const unsigned short* __restrict__ W3t,
        const float* __restrict__ b3,
        unsigned int* __restrict__ out) {
    __shared__ __align__(16) unsigned short m1_lds[64 * 136];
    __shared__ __align__(16) unsigned short m2_lds[64 * 136];
    __shared__ int s_dst[2][64];

    int tid = threadIdx.x;
    int w = tid >> 6, lane = tid & 63;
    int lr = lane & 15, q = lane >> 4;
    int tr = tid >> 4;
    int c = (tid & 15) * 8;

    bf16x8 b3f[2][4];
    float b3v[2];
    #pragma unroll
    for (int ct = 0; ct < 2; ct++) {
        int n = (2 * w + ct) * 16 + lr;
        #pragma unroll
        for (int kt = 0; kt < 4; kt++)
            b3f[ct][kt] = __builtin_bit_cast(bf16x8, *(const u32x4*)(&W3t[n * 128 + kt * 32 + q * 8]));
        b3v[ct] = b3[n];
    }

    int tb = blockIdx.x;
    int sel = 0;
    int2 pr[4];
    {
        int eb = tb * 64;
        #pragma unroll
        for (int it = 0; it < 4; it++) pr[it] = spair[eb + tr + 16 * it];
    }

    for (; tb < NTILES; tb += gridDim.x) {
        #pragma unroll
        for (int it = 0; it < 4; it++) {
            int t = tr + 16 * it;
            u32x4 ga = *(const u32x4*)(&gA[(size_t)pr[it].y * DIM + c]);
            u32x4 gb = *(const u32x4*)(&gB[(size_t)pr[it].x * DIM + c]);
            u32x4 m;
            #pragma unroll
            for (int jj = 0; jj < 4; jj++) {
                float lo = __uint_as_float(ga[jj] << 16) + __uint_as_float(gb[jj] << 16);
                float hi = __uint_as_float(ga[jj] & 0xffff0000u) + __uint_as_float(gb[jj] & 0xffff0000u);
                m[jj] = pack_bf2(fmaxf(lo, 0.f), fmaxf(hi, 0.f));
            }
            *(u32x4*)(&m1_lds[t * 136 + c]) = m;
        }
        if ((tid & 15) == 0) {
            #pragma unroll
            for (int it = 0; it < 4; it++) s_dst[sel][tr + 16 * it] = pr[it].y;
        }
        __syncthreads();   // (1) m1 ready; also orders segmax(t-1) before m2 writes(t)

        int nx = tb + (int)gridDim.x;
        int2 npr[4];
        if (nx < NTILES) {
            int eb = nx * 64;
            #pragma unroll
            for (int it = 0; it < 4; it++) npr[it] = spair[eb + tr + 16 * it];
        }

        f32x4 acc2[4][2];
        #pragma unroll
        for (int rt = 0; rt < 4; rt++)
            #pragma unroll
            for (int ct = 0; ct < 2; ct++) acc2[rt][ct] = (f32x4){0.f, 0.f, 0.f, 0.f};
        #pragma unroll
        for (int kt = 0; kt < 4; kt++) {
            #pragma unroll
            for (int rt = 0; rt < 4; rt++) {
                bf16x8 a = __builtin_bit_cast(bf16x8,
                    *(const u32x4*)(&m1_lds[(rt * 16 + lr) * 136 + kt * 32 + q * 8]));
                acc2[rt][0] = __builtin_amdgcn_mfma_f32_16x16x32_bf16(a, b3f[0][kt], acc2[rt][0], 0, 0, 0);
                acc2[rt][1] = __builtin_amdgcn_mfma_f32_16x16x32_bf16(a, b3f[1][kt], acc2[rt][1], 0, 0, 0);
            }
        }
        #pragma unroll
        for (int rt = 0; rt < 4; rt++) {
            #pragma unroll
            for (int ct = 0; ct < 2; ct++) {
                int col = (2 * w + ct) * 16 + lr;
                #pragma unroll
                for (int r = 0; r < 4; r++)
                    m2_lds[(rt * 16 + q * 4 + r) * 136 + col] = f2bf_hw(fmaxf(acc2[rt][ct][r] + b3v[ct], 0.f));
            }
        }
        __syncthreads();   // (2) m2 ready

        // segmax: thread -> (col pair = tid&63, row group = tid>>6 of 16 rows)
        {
            int pair = tid & 63;
            int g = tid >> 6;                           // == wave index
            const unsigned* m2p = (const unsigned*)m2_lds;   // [64][68] dwords
            int r0 = g * 16;
            unsigned cur = m2p[r0 * 68 + pair];
            int d = s_dst[sel][r0];                     // wave-uniform
            #pragma unroll 4
            for (int i = 1; i < 16; i++) {
                int dn = s_dst[sel][r0 + i];            // wave-uniform
                unsigned v = m2p[(r0 + i) * 68 + pair];
                if (dn != d) {                          // wave-uniform branch
                    atomicMax(&out[(size_t)d * DIM + 2 * pair],     (cur & 0xffffu) << 16);
                    atomicMax(&out[(size_t)d * DIM + 2 * pair + 1], cur & 0xffff0000u);
                    d = dn; cur = v;
                } else {
                    s16x2 a2 = __builtin_bit_cast(s16x2, cur);
                    s16x2 b2 = __builtin_bit_cast(s16x2, v);
                    cur = __builtin_bit_cast(unsigned, __builtin_elementwise_max(a2, b2));
                }
            }
            atomicMax(&out[(size_t)d * DIM + 2 * pair],     (cur & 0xffffu) << 16);
            atomicMax(&out[(size_t)d * DIM + 2 * pair + 1], cur & 0xffff0000u);
        }
        // no trailing barrier: next iter's m1/s_dst[sel^1] writes don't touch m2/s_dst[sel]

        sel ^= 1;
        #pragma unroll
        for (int it = 0; it < 4; it++) pr[it] = npr[it];
    }
}

extern "C" void kernel_launch(void* const* d_in, const int* in_sizes, int n_in,
                              void* d_out, int out_size, void* d_ws, size_t ws_size,
                              hipStream_t stream) {
    const float* x  = (const float*)d_in[0];
    const int* eidx = (const int*)d_in[1];
    const float* W1 = (const float*)d_in[2];
    const float* b1 = (const float*)d_in[3];
    const float* W2 = (const float*)d_in[4];
    const float* b2 = (const float*)d_in[5];
    const float* W3 = (const float*)d_in[6];
    const float* b3 = (const float*)d_in[7];

    char* ws = (char*)d_ws;
    unsigned short* gA  = (unsigned short*)ws;                     // 12,800,000 B
    unsigned short* gB  = (unsigned short*)(ws + 12800000);        // 12,800,000 B
    unsigned short* W1t = (unsigned short*)(ws + 25600000);        // 32,768 B
    unsigned short* Wat = (unsigned short*)(ws + 25632768);        // 32,768 B
    unsigned short* Wbt = (unsigned short*)(ws + 25665536);        // 32,768 B
    unsigned short* W3t = (unsigned short*)(ws + 25698304);        // 32,768 B
    int* cnt            = (int*)(ws + 25731072);                   // 200,000 B
    int* aux            = (int*)(ws + 25931072);                   // 1,024 B
    int2* spair         = (int2*)(ws + 25932096);                  // 6,400,000 B -> 32,332,096 total

    (void)hipMemsetAsync(cnt, 0, N_NODES * sizeof(int), stream);
    prep_kernel<<<256 + HIST_B + OUTZ_B, 256, 0, stream>>>(W1, W2, W3, eidx,
        W1t, Wat, Wbt, W3t, cnt, (u32x4*)d_out);
    scan_node_kernel<<<SCAN_B + NODE_B, 256, 0, stream>>>(cnt, aux,
        x, W1t, Wat, Wbt, b1, b2, gA, gB);
    scatter_kernel<<<SCAT_B, 256, 0, stream>>>(eidx, cnt, aux, spair);
    edge_kernel<<<2048, 256, 0, stream>>>(gA, gB, spair, W3t, b3, (unsigned int*)d_out);
}

// Round 16
// 255.334 us; speedup vs baseline: 4.4849x; 1.0675x over previous
//
#include <hip/hip_runtime.h>
#include <hip/hip_bf16.h>

#define N_NODES 50000
#define N_EDGES 800000
#define DIM 128
#define NTILES (N_EDGES / 64)   // 12500 exactly
#define SCAN_B 196              // ceil(50000/256)
#define HIST_B 3125             // 800000/256
#define NODE_B 782              // ceil(50000/64)
#define OUTZ_B 512
#define SCAT_B 2048             // 8 sets x 256 blocks; set = bid&7 -> XCD heuristic

typedef __bf16 bf16x8 __attribute__((ext_vector_type(8)));
typedef float f32x4 __attribute__((ext_vector_type(4)));
typedef unsigned int u32x4 __attribute__((ext_vector_type(4)));
typedef short s16x2 __attribute__((ext_vector_type(2)));

__device__ __forceinline__ unsigned short f2bf(float f) {
    unsigned u = __float_as_uint(f);
    u += 0x7fffu + ((u >> 16) & 1u);          // round-to-nearest-even
    return (unsigned short)(u >> 16);
}
__device__ __forceinline__ float bf2f(unsigned short s) {
    return __uint_as_float(((unsigned)s) << 16);
}
__device__ __forceinline__ unsigned short f2bf_hw(float f) {
    __hip_bfloat16 h = __float2bfloat16(f);
    unsigned short s;
    __builtin_memcpy(&s, &h, 2);
    return s;
}
// packed bf16x2 add (v_pk_add_bf16 on gfx950) + relu via packed int16 max
// (bf16 bits: negative => sign bit => int16<0, positive ordering == float ordering)
__device__ __forceinline__ unsigned bf2_add_relu(unsigned a, unsigned b) {
    __hip_bfloat162 A, B;
    __builtin_memcpy(&A, &a, 4);
    __builtin_memcpy(&B, &b, 4);
    __hip_bfloat162 S = __hadd2(A, B);
    unsigned s;
    __builtin_memcpy(&s, &S, 4);
    s16x2 sv = __builtin_bit_cast(s16x2, s);
    s16x2 z = (s16x2){0, 0};
    return __builtin_bit_cast(unsigned, __builtin_elementwise_max(sv, z));
}

// ---- K1 (R12-proven): convert weights (blocks 0..255) + dst hist (256..3380) + zero out
// identity: [h_i, h_j-h_i] @ W2 = h_i @ (W2a - W2b) + h_j @ W2b
__global__ void prep_kernel(const float* __restrict__ W1, const float* __restrict__ W2,
                            const float* __restrict__ W3, const int* __restrict__ eidx,
                            unsigned short* __restrict__ W1t, unsigned short* __restrict__ Wat,
                            unsigned short* __restrict__ Wbt, unsigned short* __restrict__ W3t,
                            int* __restrict__ cnt, u32x4* __restrict__ outz) {
    int bid = blockIdx.x, tid = threadIdx.x;
    if (bid < 256) {
        int i = bid * 256 + tid;
        int j = i & (DIM * DIM - 1);
        int k = j >> 7, n = j & 127;
        int sec = i >> 14;
        if (sec == 0)      W1t[n * 128 + k] = f2bf(W1[k * 128 + n]);
        else if (sec == 1) Wat[n * 128 + k] = f2bf(W2[k * 128 + n] - W2[(k + 128) * 128 + n]);
        else if (sec == 2) Wbt[n * 128 + k] = f2bf(W2[(k + 128) * 128 + n]);
        else               W3t[n * 128 + k] = f2bf(W3[k * 128 + n]);
    } else if (bid < 256 + HIST_B) {
        int e = (bid - 256) * 256 + tid;      // exactly covers 800000
        atomicAdd(&cnt[eidx[N_EDGES + e]], 1);
    } else {
        int b = bid - 256 - HIST_B;
        u32x4 z = (u32x4){0u, 0u, 0u, 0u};
        for (int i = b * 256 + tid; i < N_NODES * DIM / 4; i += OUTZ_B * 256) outz[i] = z;
    }
}

// ---- K2 (R12-proven): scanA (blocks 0..195) + node GEMMs (blocks 196..977)
// node: h = bf16(x@W1+b1) -> LDS -> gA = bf16(h@Wa + b2), gB = bf16(h@Wb)
__global__ __launch_bounds__(256, 2) void scan_node_kernel(
        int* __restrict__ cnt, int* __restrict__ aux,
        const float* __restrict__ x, const unsigned short* __restrict__ W1t,
        const unsigned short* __restrict__ Wat, const unsigned short* __restrict__ Wbt,
        const float* __restrict__ b1, const float* __restrict__ b2,
        unsigned short* __restrict__ gA, unsigned short* __restrict__ gB) {
    __shared__ __align__(16) unsigned short w1t[128 * 136];   // head doubles as scan buf
    __shared__ __align__(16) unsigned short h_lds[64 * 136];
    int tid = threadIdx.x, bid = blockIdx.x;
    if (bid < SCAN_B) {
        int* buf = (int*)w1t;
        int i = bid * 256 + tid;
        int v = (i < N_NODES) ? cnt[i] : 0;
        buf[tid] = v;
        __syncthreads();
        for (int off = 1; off < 256; off <<= 1) {
            int u = (tid >= off) ? buf[tid - off] : 0;
            __syncthreads();
            buf[tid] += u;
            __syncthreads();
        }
        if (i < N_NODES) cnt[i] = buf[tid] - v;
        if (tid == 255) aux[bid] = buf[255];
        return;
    }
    int bl = bid - SCAN_B;
    #pragma unroll
    for (int it = 0; it < 8; it++) {
        int idx = (tid + it * 256) * 8;
        int n = idx >> 7, k = idx & 127;
        *(u32x4*)(&w1t[n * 136 + k]) = *(const u32x4*)(&W1t[idx]);
    }
    int w = tid >> 6, lane = tid & 63;
    int lr = lane & 15, q = lane >> 4;
    bf16x8 baf[2][4], bbf[2][4];
    float b2v[2];
    #pragma unroll
    for (int ct = 0; ct < 2; ct++) {
        int n = (2 * w + ct) * 16 + lr;
        #pragma unroll
        for (int kt = 0; kt < 4; kt++) {
            baf[ct][kt] = __builtin_bit_cast(bf16x8, *(const u32x4*)(&Wat[n * 128 + kt * 32 + q * 8]));
            bbf[ct][kt] = __builtin_bit_cast(bf16x8, *(const u32x4*)(&Wbt[n * 128 + kt * 32 + q * 8]));
        }
        b2v[ct] = b2[n];
    }
    __syncthreads();
    int row0 = bl * 64;
    int rowA = row0 + w * 16 + lr; if (rowA >= N_NODES) rowA = N_NODES - 1;
    {
        f32x4 acc[8];
        #pragma unroll
        for (int ct = 0; ct < 8; ct++) acc[ct] = (f32x4){0.f, 0.f, 0.f, 0.f};
        #pragma unroll
        for (int kt = 0; kt < 4; kt++) {
            const float* ap = x + (size_t)rowA * DIM + kt * 32 + q * 8;
            f32x4 x0 = *(const f32x4*)(ap);
            f32x4 x1 = *(const f32x4*)(ap + 4);
            bf16x8 a;
            #pragma unroll
            for (int j = 0; j < 4; j++) { a[j] = (__bf16)x0[j]; a[j + 4] = (__bf16)x1[j]; }
            #pragma unroll
            for (int ct = 0; ct < 8; ct++) {
                bf16x8 b = __builtin_bit_cast(bf16x8,
                    *(const u32x4*)(&w1t[(ct * 16 + lr) * 136 + kt * 32 + q * 8]));
                acc[ct] = __builtin_amdgcn_mfma_f32_16x16x32_bf16(a, b, acc[ct], 0, 0, 0);
            }
        }
        #pragma unroll
        for (int ct = 0; ct < 8; ct++) {
            int col = ct * 16 + lr;
            float bias = b1[col];
            #pragma unroll
            for (int r = 0; r < 4; r++)   // C/D: col=lane&15, row=quad*4+reg
                h_lds[(w * 16 + q * 4 + r) * 136 + col] = f2bf(acc[ct][r] + bias);
        }
    }
    __syncthreads();
    {
        f32x4 accA[4][2], accB[4][2];
        #pragma unroll
        for (int rt = 0; rt < 4; rt++)
            #pragma unroll
            for (int ct = 0; ct < 2; ct++) {
                accA[rt][ct] = (f32x4){0.f, 0.f, 0.f, 0.f};
                accB[rt][ct] = (f32x4){0.f, 0.f, 0.f, 0.f};
            }
        #pragma unroll
        for (int kt = 0; kt < 4; kt++) {
            #pragma unroll
            for (int rt = 0; rt < 4; rt++) {
                bf16x8 a = __builtin_bit_cast(bf16x8,
                    *(const u32x4*)(&h_lds[(rt * 16 + lr) * 136 + kt * 32 + q * 8]));
                accA[rt][0] = __builtin_amdgcn_mfma_f32_16x16x32_bf16(a, baf[0][kt], accA[rt][0], 0, 0, 0);
                accA[rt][1] = __builtin_amdgcn_mfma_f32_16x16x32_bf16(a, baf[1][kt], accA[rt][1], 0, 0, 0);
                accB[rt][0] = __builtin_amdgcn_mfma_f32_16x16x32_bf16(a, bbf[0][kt], accB[rt][0], 0, 0, 0);
                accB[rt][1] = __builtin_amdgcn_mfma_f32_16x16x32_bf16(a, bbf[1][kt], accB[rt][1], 0, 0, 0);
            }
        }
        #pragma unroll
        for (int rt = 0; rt < 4; rt++) {
            #pragma unroll
            for (int ct = 0; ct < 2; ct++) {
                int col = (2 * w + ct) * 16 + lr;
                #pragma unroll
                for (int r = 0; r < 4; r++) {
                    int row = row0 + rt * 16 + q * 4 + r;
                    if (row < N_NODES) {
                        gA[(size_t)row * DIM + col] = f2bf(accA[rt][ct][r] + b2v[ct]);
                        gB[(size_t)row * DIM + col] = f2bf(accB[rt][ct][r]);
                    }
                }
            }
        }
    }
}

// ---- K3 (R12-proven): XCD-binned scatter
__global__ __launch_bounds__(256) void scatter_kernel(
        const int* __restrict__ eidx, int* __restrict__ cursor, const int* __restrict__ aux,
        int2* __restrict__ spair) {
    __shared__ int buf[256];
    int tid = threadIdx.x, bid = blockIdx.x;
    int v = (tid < SCAN_B) ? aux[tid] : 0;
    buf[tid] = v;
    __syncthreads();
    for (int off = 1; off < 256; off <<= 1) {
        int u = (tid >= off) ? buf[tid - off] : 0;
        __syncthreads();
        buf[tid] += u;
        __syncthreads();
    }
    int excl = buf[tid] - v;
    __syncthreads();
    buf[tid] = excl;
    __syncthreads();
    int set = bid & 7;
    int j = bid >> 3;
    for (int e = j * 256 + tid; e < N_EDGES; e += (SCAT_B / 8) * 256) {
        int d = eidx[N_EDGES + e];
        if (((d >> 8) & 7) == set) {
            int s = eidx[e];
            int p = atomicAdd(&cursor[d], 1) + buf[d >> 8];
            spair[p] = make_int2(s, d);
        }
    }
}

// ---- K4: edge = relu(gA[dst]+gB[src]) -> GEMM2 -> segmented scatter-max.
// m1 pack: v_pk_add_bf16 + packed-int relu (2 ops/dword vs 6).
// segmax: R12 geometry (2 groups of 32 rows -> same boundary/atomic count as R12),
// packed s16x2 max, 64 col-pairs, threads 0..127 only (waves 0-1, wave-uniform).
__global__ __launch_bounds__(256, 4) void edge_kernel(
        const unsigned short* __restrict__ gA,
        const unsigned short* __restrict__ gB,
        const int2* __restrict__ spair,
        const unsigned short* __restrict__ W3t,
        const float* __restrict__ b3,
        unsigned int* __restrict__ out) {
    __shared__ __align__(16) unsigned short m1_lds[64 * 136];
    __shared__ __align__(16) unsigned short m2_lds[64 * 136];
    __shared__ int s_dst[2][64];

    int tid = threadIdx.x;
    int w = tid >> 6, lane = tid & 63;
    int lr = lane & 15, q = lane >> 4;
    int tr = tid >> 4;
    int c = (tid & 15) * 8;

    bf16x8 b3f[2][4];
    float b3v[2];
    #pragma unroll
    for (int ct = 0; ct < 2; ct++) {
        int n = (2 * w + ct) * 16 + lr;
        #pragma unroll
        for (int kt = 0; kt < 4; kt++)
            b3f[ct][kt] = __builtin_bit_cast(bf16x8, *(const u32x4*)(&W3t[n * 128 + kt * 32 + q * 8]));
        b3v[ct] = b3[n];
    }

    int tb = blockIdx.x;
    int sel = 0;
    int2 pr[4];
    {
        int eb = tb * 64;
        #pragma unroll
        for (int it = 0; it < 4; it++) pr[it] = spair[eb + tr + 16 * it];
    }

    for (; tb < NTILES; tb += gridDim.x) {
        // m1 = relu(gA[dst]+gB[src]) — packed bf16 add + packed int relu
        #pragma unroll
        for (int it = 0; it < 4; it++) {
            int t = tr + 16 * it;
            u32x4 ga = *(const u32x4*)(&gA[(size_t)pr[it].y * DIM + c]);
            u32x4 gb = *(const u32x4*)(&gB[(size_t)pr[it].x * DIM + c]);
            u32x4 m;
            #pragma unroll
            for (int jj = 0; jj < 4; jj++)
                m[jj] = bf2_add_relu(ga[jj], gb[jj]);
            *(u32x4*)(&m1_lds[t * 136 + c]) = m;
        }
        if ((tid & 15) == 0) {
            #pragma unroll
            for (int it = 0; it < 4; it++) s_dst[sel][tr + 16 * it] = pr[it].y;
        }
        __syncthreads();   // (1) m1 ready; also orders segmax(t-1) before m2 writes(t)

        int nx = tb + (int)gridDim.x;
        int2 npr[4];
        if (nx < NTILES) {
            int eb = nx * 64;
            #pragma unroll
            for (int it = 0; it < 4; it++) npr[it] = spair[eb + tr + 16 * it];
        }

        f32x4 acc2[4][2];
        #pragma unroll
        for (int rt = 0; rt < 4; rt++)
            #pragma unroll
            for (int ct = 0; ct < 2; ct++) acc2[rt][ct] = (f32x4){0.f, 0.f, 0.f, 0.f};
        #pragma unroll
        for (int kt = 0; kt < 4; kt++) {
            #pragma unroll
            for (int rt = 0; rt < 4; rt++) {
                bf16x8 a = __builtin_bit_cast(bf16x8,
                    *(const u32x4*)(&m1_lds[(rt * 16 + lr) * 136 + kt * 32 + q * 8]));
                acc2[rt][0] = __builtin_amdgcn_mfma_f32_16x16x32_bf16(a, b3f[0][kt], acc2[rt][0], 0, 0, 0);
                acc2[rt][1] = __builtin_amdgcn_mfma_f32_16x16x32_bf16(a, b3f[1][kt], acc2[rt][1], 0, 0, 0);
            }
        }
        #pragma unroll
        for (int rt = 0; rt < 4; rt++) {
            #pragma unroll
            for (int ct = 0; ct < 2; ct++) {
                int col = (2 * w + ct) * 16 + lr;
                #pragma unroll
                for (int r = 0; r < 4; r++)
                    m2_lds[(rt * 16 + q * 4 + r) * 136 + col] = f2bf_hw(fmaxf(acc2[rt][ct][r] + b3v[ct], 0.f));
            }
        }
        __syncthreads();   // (2) m2 ready

        // segmax: threads 0..127 -> (col pair = tid&63, row group = tid>>6 of 32 rows)
        if (tid < 128) {
            int pair = tid & 63;
            int g = tid >> 6;                           // == wave index (0 or 1)
            const unsigned* m2p = (const unsigned*)m2_lds;   // [64][68] dwords
            int r0 = g * 32;
            unsigned cur = m2p[r0 * 68 + pair];
            int d = s_dst[sel][r0];                     // wave-uniform
            #pragma unroll 4
            for (int i = 1; i < 32; i++) {
                int dn = s_dst[sel][r0 + i];            // wave-uniform
                unsigned v = m2p[(r0 + i) * 68 + pair];
                if (dn != d) {                          // wave-uniform branch
                    atomicMax(&out[(size_t)d * DIM + 2 * pair],     (cur & 0xffffu) << 16);
                    atomicMax(&out[(size_t)d * DIM + 2 * pair + 1], cur & 0xffff0000u);
                    d = dn; cur = v;
                } else {
                    s16x2 a2 = __builtin_bit_cast(s16x2, cur);
                    s16x2 b2 = __builtin_bit_cast(s16x2, v);
                    cur = __builtin_bit_cast(unsigned, __builtin_elementwise_max(a2, b2));
                }
            }
            atomicMax(&out[(size_t)d * DIM + 2 * pair],     (cur & 0xffffu) << 16);
            atomicMax(&out[(size_t)d * DIM + 2 * pair + 1], cur & 0xffff0000u);
        }
        // no trailing barrier: next iter's m1/s_dst[sel^1] writes don't touch m2/s_dst[sel];
        // waves 2-3 run ahead into the next gather while waves 0-1 finish segmax.

        sel ^= 1;
        #pragma unroll
        for (int it = 0; it < 4; it++) pr[it] = npr[it];
    }
}

extern "C" void kernel_launch(void* const* d_in, const int* in_sizes, int n_in,
                              void* d_out, int out_size, void* d_ws, size_t ws_size,
                              hipStream_t stream) {
    const float* x  = (const float*)d_in[0];
    const int* eidx = (const int*)d_in[1];
    const float* W1 = (const float*)d_in[2];
    const float* b1 = (const float*)d_in[3];
    const float* W2 = (const float*)d_in[4];
    const float* b2 = (const float*)d_in[5];
    const float* W3 = (const float*)d_in[6];
    const float* b3 = (const float*)d_in[7];

    char* ws = (char*)d_ws;
    unsigned short* gA  = (unsigned short*)ws;                     // 12,800,000 B
    unsigned short* gB  = (unsigned short*)(ws + 12800000);        // 12,800,000 B
    unsigned short* W1t = (unsigned short*)(ws + 25600000);        // 32,768 B
    unsigned short* Wat = (unsigned short*)(ws + 25632768);        // 32,768 B
    unsigned short* Wbt = (unsigned short*)(ws + 25665536);        // 32,768 B
    unsigned short* W3t = (unsigned short*)(ws + 25698304);        // 32,768 B
    int* cnt            = (int*)(ws + 25731072);                   // 200,000 B
    int* aux            = (int*)(ws + 25931072);                   // 1,024 B
    int2* spair         = (int2*)(ws + 25932096);                  // 6,400,000 B -> 32,332,096 total

    (void)hipMemsetAsync(cnt, 0, N_NODES * sizeof(int), stream);
    prep_kernel<<<256 + HIST_B + OUTZ_B, 256, 0, stream>>>(W1, W2, W3, eidx,
        W1t, Wat, Wbt, W3t, cnt, (u32x4*)d_out);
    scan_node_kernel<<<SCAN_B + NODE_B, 256, 0, stream>>>(cnt, aux,
        x, W1t, Wat, Wbt, b1, b2, gA, gB);
    scatter_kernel<<<SCAT_B, 256, 0, stream>>>(eidx, cnt, aux, spair);
    edge_kernel<<<2048, 256, 0, stream>>>(gA, gB, spair, W3t, b3, (unsigned int*)d_out);
}